// Round 13
// baseline (69.718 us; speedup 1.0000x reference)
//
#include <hip/hip_runtime.h>

#define B_ 4
#define C_ 64
#define H_ 96
#define W_ 96
#define KS_ 7
#define NPIX (H_ * W_)     // 9216
#define PR_ 102            // padded rows
#define PC_ 104            // padded row stride (ushorts), 16B-aligned
#define PSLAB (PR_ * PC_)  // 10608 per (tensor,ch)

typedef __attribute__((ext_vector_type(8))) short short8;
typedef __attribute__((ext_vector_type(8))) unsigned short ushort8;
typedef __attribute__((ext_vector_type(4))) float f32x4;

static __device__ inline ushort f2bf(float f) {
    union { float f; unsigned u; } v; v.f = f;
    unsigned r = (v.u + 0x7fff + ((v.u >> 16) & 1)) >> 16;   // RNE
    return (ushort)r;
}
static __device__ inline float bf2f(ushort u) {
    union { unsigned u; float f; } v; v.u = ((unsigned)u) << 16; return v.f;
}

// ws: qf float[B][64][9216] ; kvb ushort[B][2][64][102][104] ; rel float[64]

__global__ __launch_bounds__(256) void mfma_conv_kernel(
    const float* __restrict__ in,
    const float* __restrict__ qw, const float* __restrict__ qb,
    const float* __restrict__ kw, const float* __restrict__ kb,
    const float* __restrict__ vw, const float* __restrict__ vb,
    const float* __restrict__ relh, const float* __restrict__ relw,
    float* __restrict__ qf, ushort* __restrict__ kvb, float* __restrict__ rel_out)
{
    const int b    = blockIdx.y;
    const int pix0 = blockIdx.x * 32;
    const int t    = threadIdx.x;
    const int lane = t & 63;
    const int wv   = t >> 6;

    if (blockIdx.x == 0 && b == 0 && t < 49) {   // rel precompute
        const int i = t / KS_, j = t % KS_;
        float s = 0.f;
        #pragma unroll
        for (int cc = 0; cc < C_ / 2; ++cc)
            s += relh[cc * KS_ + i] + relw[cc * KS_ + j];
        rel_out[t] = s;
    }

    // border fill for this b: 2 tensors x 64 ch x 1200 cells = 153600 cells
    {
        const int base = blockIdx.x * 256 + t;
        #pragma unroll
        for (int rep = 0; rep < 3; ++rep) {
            const int idx = base + rep * 73728;
            if (idx < 153600) {
                const int cell   = idx % 1200;
                const int chh    = (idx / 1200) & 63;
                const int tensor = idx / 76800;
                int pr, pw;
                if (cell < 312)      { pr = cell / PC_;              pw = cell % PC_; }
                else if (cell < 624) { int j2 = cell - 312; pr = 99 + j2 / PC_; pw = j2 % PC_; }
                else                 { int j2 = cell - 624; pr = 3 + j2 / 6; int s2 = j2 % 6;
                                       pw = (s2 < 3) ? s2 : 96 + s2; }
                const float bias = (tensor ? vb : kb)[chh];
                kvb[((size_t)(b * 2 + tensor) * C_ + chh) * PSLAB + pr * PC_ + pw] = f2bf(bias);
            }
        }
    }

    __shared__ ushort xs[32 * 64];   // [pix][ch] bf16, byte ^= (pix&7)<<4

    {   // stage X tile (32 pix x 64 ch)
        const int pix = t & 31, cg = t >> 5;
        const float* xp = in + (size_t)b * C_ * NPIX + pix0 + pix;
        #pragma unroll
        for (int g = 0; g < 2; ++g) {
            const int ch = (cg + 8 * g) * 4;
            float x0 = xp[(size_t)(ch    ) * NPIX];
            float x1 = xp[(size_t)(ch + 1) * NPIX];
            float x2 = xp[(size_t)(ch + 2) * NPIX];
            float x3 = xp[(size_t)(ch + 3) * NPIX];
            ushort4 u = make_ushort4(f2bf(x0), f2bf(x1), f2bf(x2), f2bf(x3));
            unsigned byte = (unsigned)(pix * 128 + ch * 2) ^ (unsigned)((pix & 7) << 4);
            *reinterpret_cast<ushort4*>(reinterpret_cast<char*>(xs) + byte) = u;
        }
    }

    short8 afr[3][2];
    float  bi[3][4];
    #pragma unroll
    for (int i = 0; i < 3; ++i) {
        const int mt  = 3 * wv + i;
        const int row = mt * 16 + (lane & 15);
        const float* wsrc = (mt < 4) ? qw + row * 64
                          : (mt < 8) ? kw + (row - 64) * 64
                                     : vw + (row - 128) * 64;
        #pragma unroll
        for (int ka = 0; ka < 2; ++ka) {
            const int kk = ka * 32 + (lane >> 4) * 8;
            float4 a = *reinterpret_cast<const float4*>(wsrc + kk);
            float4 c = *reinterpret_cast<const float4*>(wsrc + kk + 4);
            short8 s;
            s[0] = (short)f2bf(a.x); s[1] = (short)f2bf(a.y);
            s[2] = (short)f2bf(a.z); s[3] = (short)f2bf(a.w);
            s[4] = (short)f2bf(c.x); s[5] = (short)f2bf(c.y);
            s[6] = (short)f2bf(c.z); s[7] = (short)f2bf(c.w);
            afr[i][ka] = s;
        }
        const int brow = mt * 16 + (lane >> 4) * 4;
        const float* bsrc = (mt < 4) ? qb + brow
                          : (mt < 8) ? kb + (brow - 64)
                                     : vb + (brow - 128);
        #pragma unroll
        for (int r = 0; r < 4; ++r) bi[i][r] = bsrc[r];
    }
    __syncthreads();

    short8 bfr[2][2];
    #pragma unroll
    for (int nt = 0; nt < 2; ++nt) {
        const int pl = nt * 16 + (lane & 15);
        #pragma unroll
        for (int ka = 0; ka < 2; ++ka) {
            const int kk = ka * 32 + (lane >> 4) * 8;
            unsigned byte = (unsigned)(pl * 128 + kk * 2) ^ (unsigned)((pl & 7) << 4);
            bfr[nt][ka] = *reinterpret_cast<const short8*>(
                reinterpret_cast<const char*>(xs) + byte);
        }
    }
    f32x4 acc[3][2];
    #pragma unroll
    for (int i = 0; i < 3; ++i) {
        f32x4 bv;
        #pragma unroll
        for (int r = 0; r < 4; ++r) bv[r] = bi[i][r];
        #pragma unroll
        for (int nt = 0; nt < 2; ++nt) acc[i][nt] = bv;
    }
    #pragma unroll
    for (int i = 0; i < 3; ++i) {
        #pragma unroll
        for (int nt = 0; nt < 2; ++nt) {
            acc[i][nt] = __builtin_amdgcn_mfma_f32_16x16x32_bf16(
                afr[i][0], bfr[nt][0], acc[i][nt], 0, 0, 0);
            acc[i][nt] = __builtin_amdgcn_mfma_f32_16x16x32_bf16(
                afr[i][1], bfr[nt][1], acc[i][nt], 0, 0, 0);
        }
    }
    #pragma unroll
    for (int i = 0; i < 3; ++i) {
        const int mt = 3 * wv + i;
        #pragma unroll
        for (int nt = 0; nt < 2; ++nt) {
            const int pix = pix0 + nt * 16 + (lane & 15);
            const int h = pix / 96, w = pix - h * 96;
            #pragma unroll
            for (int r = 0; r < 4; ++r) {
                const int row = mt * 16 + (lane >> 4) * 4 + r;
                if (mt < 4) {
                    qf[((size_t)b * C_ + row) * NPIX + pix] = acc[i][nt][r];
                } else {
                    const int tensor = (mt < 8) ? 0 : 1;
                    const int ch = (mt & 3) * 16 + (lane >> 4) * 4 + r;
                    kvb[((size_t)(b * 2 + tensor) * C_ + ch) * PSLAB
                        + (h + 3) * PC_ + (w + 3)] = f2bf(acc[i][nt][r]);
                }
            }
        }
    }
}

// ---- attention: REP x3 for counter visibility (stage once, compute 3x) ----
__global__ __launch_bounds__(384) void attn_kernel(
    const float* __restrict__ qf, const ushort* __restrict__ kvb,
    const float* __restrict__ rel, float* __restrict__ out)
{
    const int bx   = blockIdx.x;
    const int tile = bx % 3;
    const int c    = (bx / 3) % C_;
    const int b    = bx / (3 * C_);
    const int ho0  = tile * 32;
    const int t    = threadIdx.x;

    __shared__ __align__(16) ushort kvls[2][38 * PC_];

    {
        const ushort* kbase = kvb + ((size_t)(b * 2 + 0) * C_ + c) * PSLAB + ho0 * PC_;
        const ushort* vbase = kvb + ((size_t)(b * 2 + 1) * C_ + c) * PSLAB + ho0 * PC_;
        #pragma unroll
        for (int s0 = 0; s0 < 3; ++s0) {
            const int idx = t + s0 * 384;
            if (idx < 988) {
                const int tensor = idx >= 494;
                const int off = (tensor ? idx - 494 : idx) * 8;
                const ushort* src = (tensor ? vbase : kbase) + off;
                *reinterpret_cast<ushort8*>(&kvls[tensor][off]) =
                    *reinterpret_cast<const ushort8*>(src);
            }
        }
    }
    __syncthreads();

    const int r0   = t / 12;
    const int rest = t % 12;
    const int w0   = (rest >> 1) * 16;
    const int half = rest & 1;
    const int ho   = ho0 + r0;

    const float LOG2E = 1.44269504f;
    const float* qp = qf + ((size_t)b * C_ + c) * NPIX + ho * W_ + w0;
    float* op = out + (((size_t)b * C_ + c) * H_ + ho) * W_ + w0 + half * 8;

    // MEASUREMENT: rep x3 (identical work+stores); roff==0 but opaque (rule #17).
    int roff = 0;
    #pragma unroll 1
    for (int rep = 0; rep < 3; ++rep) {
        asm volatile("" : "+v"(roff));

        float qs[16];
        #pragma unroll
        for (int tt = 0; tt < 16; tt += 4) {
            float4 f = *reinterpret_cast<const float4*>(qp + tt + roff);
            qs[tt] = f.x * LOG2E; qs[tt + 1] = f.y * LOG2E;
            qs[tt + 2] = f.z * LOG2E; qs[tt + 3] = f.w * LOG2E;
        }
        float qsum = 0.f;
        #pragma unroll
        for (int tt = 0; tt < 16; ++tt) qsum += qs[tt];

        float p[49];
        #pragma unroll
        for (int i = 0; i < KS_; ++i) {
            const ushort* kp = &kvls[0][(r0 + i) * PC_ + w0 + roff];
            ushort8 u0 = *reinterpret_cast<const ushort8*>(kp);
            ushort8 u1 = *reinterpret_cast<const ushort8*>(kp + 8);
            ushort8 u2 = *reinterpret_cast<const ushort8*>(kp + 16);
            float kr[22];
            #pragma unroll
            for (int e = 0; e < 8; ++e) kr[e] = bf2f(u0[e]);
            #pragma unroll
            for (int e = 0; e < 8; ++e) kr[8 + e] = bf2f(u1[e]);
            #pragma unroll
            for (int e = 0; e < 6; ++e) kr[16 + e] = bf2f(u2[e]);
            #pragma unroll
            for (int j = 0; j < KS_; ++j) {
                float s0 = 0.f, s1 = 0.f, s2 = 0.f, s3 = 0.f;
                #pragma unroll
                for (int tt = 0; tt < 16; tt += 4) {
                    s0 = fmaf(qs[tt],     kr[tt + j],     s0);
                    s1 = fmaf(qs[tt + 1], kr[tt + 1 + j], s1);
                    s2 = fmaf(qs[tt + 2], kr[tt + 2 + j], s2);
                    s3 = fmaf(qs[tt + 3], kr[tt + 3 + j], s3);
                }
                p[i * KS_ + j] = (s0 + s1) + (s2 + s3) + qsum * rel[i * KS_ + j];
            }
        }

        float m0 = p[0], m1 = p[1], m2 = p[2], m3 = p[3];
        #pragma unroll
        for (int kk = 4; kk < 48; kk += 4) {
            m0 = fmaxf(m0, p[kk]);     m1 = fmaxf(m1, p[kk + 1]);
            m2 = fmaxf(m2, p[kk + 2]); m3 = fmaxf(m3, p[kk + 3]);
        }
        float m = fmaxf(fmaxf(fmaxf(m0, m1), fmaxf(m2, m3)), p[48]);

        float e0 = 0.f, e1 = 0.f, e2 = 0.f, e3 = 0.f;
        #pragma unroll
        for (int kk = 0; kk < 48; kk += 4) {
            float a0 = exp2f(p[kk]     - m);
            float a1 = exp2f(p[kk + 1] - m);
            float a2 = exp2f(p[kk + 2] - m);
            float a3 = exp2f(p[kk + 3] - m);
            p[kk] = a0; p[kk + 1] = a1; p[kk + 2] = a2; p[kk + 3] = a3;
            e0 += a0; e1 += a1; e2 += a2; e3 += a3;
        }
        float a48 = exp2f(p[48] - m);
        p[48] = a48;
        const float inv = 1.f / ((e0 + e1) + (e2 + e3) + a48);

        float o8[8];
        #pragma unroll
        for (int d = 0; d < 8; ++d) o8[d] = 0.f;

        #pragma unroll
        for (int i = 0; i < KS_; ++i) {
            const ushort* vp = &kvls[1][(r0 + i) * PC_ + w0 + half * 8 + roff];
            ushort8 u0 = *reinterpret_cast<const ushort8*>(vp);
            ushort8 u1 = *reinterpret_cast<const ushort8*>(vp + 8);
            float vf[14];
            #pragma unroll
            for (int e = 0; e < 8; ++e) vf[e] = bf2f(u0[e]);
            #pragma unroll
            for (int e = 0; e < 6; ++e) vf[8 + e] = bf2f(u1[e]);
            #pragma unroll
            for (int j = 0; j < KS_; ++j) {
                float wgt = p[i * KS_ + j];
                #pragma unroll
                for (int d = 0; d < 8; ++d) o8[d] = fmaf(wgt, vf[d + j], o8[d]);
            }
        }

        #pragma unroll
        for (int d = 0; d < 8; d += 4) {
            float4 f;
            f.x = fmaxf(o8[d]     * inv, 0.f);
            f.y = fmaxf(o8[d + 1] * inv, 0.f);
            f.z = fmaxf(o8[d + 2] * inv, 0.f);
            f.w = fmaxf(o8[d + 3] * inv, 0.f);
            *reinterpret_cast<float4*>(op + d) = f;
        }
    }
}

extern "C" void kernel_launch(void* const* d_in, const int* in_sizes, int n_in,
                              void* d_out, int out_size, void* d_ws, size_t ws_size,
                              hipStream_t stream) {
    const float* in   = (const float*)d_in[0];
    const float* qw   = (const float*)d_in[1];
    const float* qb   = (const float*)d_in[2];
    const float* kw   = (const float*)d_in[3];
    const float* kb   = (const float*)d_in[4];
    const float* vw   = (const float*)d_in[5];
    const float* vb   = (const float*)d_in[6];
    const float* relh = (const float*)d_in[7];
    const float* relw = (const float*)d_in[8];
    float* out = (float*)d_out;

    float*  qf  = (float*)d_ws;                            // [B][64][9216] f32
    ushort* kvb = (ushort*)(qf + (size_t)B_ * C_ * NPIX);  // [B][2][64][102][104] bf16
    float*  rel = (float*)(kvb + (size_t)B_ * 2 * C_ * PSLAB);

    dim3 cgrid(NPIX / 32, B_);   // 288 x 4 = 1152 blocks
    mfma_conv_kernel<<<cgrid, 256, 0, stream>>>(in, qw, qb, kw, kb, vw, vb,
                                                relh, relw, qf, kvb, rel);

    dim3 agrid(B_ * C_ * 3);     // 768 blocks x 384 threads
    attn_kernel<<<agrid, 384, 0, stream>>>(qf, kvb, rel, out);
}

// Round 14
// 37.640 us; speedup vs baseline: 1.8522x; 1.8522x over previous
//
#include <hip/hip_runtime.h>

#define B_ 4
#define C_ 64
#define H_ 96
#define W_ 96
#define KS_ 7
#define NPIX (H_ * W_)     // 9216
#define PR_ 102            // padded rows
#define PC_ 104            // padded row stride (floats), 16B-aligned
#define PSLAB (PR_ * PC_)  // 10608 floats per (tensor,ch)
#define LDK 108            // LDS row stride (floats): 432B -> ~2-way conflicts only

typedef __attribute__((ext_vector_type(8))) short short8;
typedef __attribute__((ext_vector_type(4))) float f32x4;

static __device__ inline ushort f2bf(float f) {
    union { float f; unsigned u; } v; v.f = f;
    unsigned r = (v.u + 0x7fff + ((v.u >> 16) & 1)) >> 16;   // RNE
    return (ushort)r;
}

// ws: qf float[B][64][9216] ; kvf float[B][2][64][102][104] (border=bias) ; rel float[64]

__global__ __launch_bounds__(256) void mfma_conv_kernel(
    const float* __restrict__ in,
    const float* __restrict__ qw, const float* __restrict__ qb,
    const float* __restrict__ kw, const float* __restrict__ kb,
    const float* __restrict__ vw, const float* __restrict__ vb,
    const float* __restrict__ relh, const float* __restrict__ relw,
    float* __restrict__ qf, float* __restrict__ kvf, float* __restrict__ rel_out)
{
    const int b    = blockIdx.y;
    const int pix0 = blockIdx.x * 32;
    const int t    = threadIdx.x;
    const int lane = t & 63;
    const int wv   = t >> 6;

    if (blockIdx.x == 0 && b == 0 && t < 49) {   // rel precompute
        const int i = t / KS_, j = t % KS_;
        float s = 0.f;
        #pragma unroll
        for (int cc = 0; cc < C_ / 2; ++cc)
            s += relh[cc * KS_ + i] + relw[cc * KS_ + j];
        rel_out[t] = s;
    }

    // border fill for this b: 2 tensors x 64 ch x 1200 cells = 153600 cells
    {
        const int base = blockIdx.x * 256 + t;
        #pragma unroll
        for (int rep = 0; rep < 3; ++rep) {
            const int idx = base + rep * 73728;
            if (idx < 153600) {
                const int cell   = idx % 1200;
                const int chh    = (idx / 1200) & 63;
                const int tensor = idx / 76800;
                int pr, pw;
                if (cell < 312)      { pr = cell / PC_;              pw = cell % PC_; }
                else if (cell < 624) { int j2 = cell - 312; pr = 99 + j2 / PC_; pw = j2 % PC_; }
                else                 { int j2 = cell - 624; pr = 3 + j2 / 6; int s2 = j2 % 6;
                                       pw = (s2 < 3) ? s2 : 96 + s2; }
                const float bias = (tensor ? vb : kb)[chh];
                kvf[((size_t)(b * 2 + tensor) * C_ + chh) * PSLAB + pr * PC_ + pw] = bias;
            }
        }
    }

    __shared__ ushort xs[32 * 64];   // [pix][ch] bf16, byte ^= (pix&7)<<4

    {   // stage X tile (32 pix x 64 ch)
        const int pix = t & 31, cg = t >> 5;
        const float* xp = in + (size_t)b * C_ * NPIX + pix0 + pix;
        #pragma unroll
        for (int g = 0; g < 2; ++g) {
            const int ch = (cg + 8 * g) * 4;
            float x0 = xp[(size_t)(ch    ) * NPIX];
            float x1 = xp[(size_t)(ch + 1) * NPIX];
            float x2 = xp[(size_t)(ch + 2) * NPIX];
            float x3 = xp[(size_t)(ch + 3) * NPIX];
            ushort4 u = make_ushort4(f2bf(x0), f2bf(x1), f2bf(x2), f2bf(x3));
            unsigned byte = (unsigned)(pix * 128 + ch * 2) ^ (unsigned)((pix & 7) << 4);
            *reinterpret_cast<ushort4*>(reinterpret_cast<char*>(xs) + byte) = u;
        }
    }

    short8 afr[3][2];
    float  bi[3][4];
    #pragma unroll
    for (int i = 0; i < 3; ++i) {
        const int mt  = 3 * wv + i;
        const int row = mt * 16 + (lane & 15);
        const float* wsrc = (mt < 4) ? qw + row * 64
                          : (mt < 8) ? kw + (row - 64) * 64
                                     : vw + (row - 128) * 64;
        #pragma unroll
        for (int ka = 0; ka < 2; ++ka) {
            const int kk = ka * 32 + (lane >> 4) * 8;
            float4 a = *reinterpret_cast<const float4*>(wsrc + kk);
            float4 c = *reinterpret_cast<const float4*>(wsrc + kk + 4);
            short8 s;
            s[0] = (short)f2bf(a.x); s[1] = (short)f2bf(a.y);
            s[2] = (short)f2bf(a.z); s[3] = (short)f2bf(a.w);
            s[4] = (short)f2bf(c.x); s[5] = (short)f2bf(c.y);
            s[6] = (short)f2bf(c.z); s[7] = (short)f2bf(c.w);
            afr[i][ka] = s;
        }
        const int brow = mt * 16 + (lane >> 4) * 4;
        const float* bsrc = (mt < 4) ? qb + brow
                          : (mt < 8) ? kb + (brow - 64)
                                     : vb + (brow - 128);
        #pragma unroll
        for (int r = 0; r < 4; ++r) bi[i][r] = bsrc[r];
    }
    __syncthreads();

    short8 bfr[2][2];
    #pragma unroll
    for (int nt = 0; nt < 2; ++nt) {
        const int pl = nt * 16 + (lane & 15);
        #pragma unroll
        for (int ka = 0; ka < 2; ++ka) {
            const int kk = ka * 32 + (lane >> 4) * 8;
            unsigned byte = (unsigned)(pl * 128 + kk * 2) ^ (unsigned)((pl & 7) << 4);
            bfr[nt][ka] = *reinterpret_cast<const short8*>(
                reinterpret_cast<const char*>(xs) + byte);
        }
    }
    f32x4 acc[3][2];
    #pragma unroll
    for (int i = 0; i < 3; ++i) {
        f32x4 bv;
        #pragma unroll
        for (int r = 0; r < 4; ++r) bv[r] = bi[i][r];
        #pragma unroll
        for (int nt = 0; nt < 2; ++nt) acc[i][nt] = bv;
    }
    #pragma unroll
    for (int i = 0; i < 3; ++i) {
        #pragma unroll
        for (int nt = 0; nt < 2; ++nt) {
            acc[i][nt] = __builtin_amdgcn_mfma_f32_16x16x32_bf16(
                afr[i][0], bfr[nt][0], acc[i][nt], 0, 0, 0);
            acc[i][nt] = __builtin_amdgcn_mfma_f32_16x16x32_bf16(
                afr[i][1], bfr[nt][1], acc[i][nt], 0, 0, 0);
        }
    }
    #pragma unroll
    for (int i = 0; i < 3; ++i) {
        const int mt = 3 * wv + i;
        #pragma unroll
        for (int nt = 0; nt < 2; ++nt) {
            const int pix = pix0 + nt * 16 + (lane & 15);
            const int h = pix / 96, w = pix - h * 96;
            #pragma unroll
            for (int r = 0; r < 4; ++r) {
                const int row = mt * 16 + (lane >> 4) * 4 + r;
                if (mt < 4) {
                    qf[((size_t)b * C_ + row) * NPIX + pix] = acc[i][nt][r];
                } else {
                    const int tensor = (mt < 8) ? 0 : 1;
                    const int ch = (mt & 3) * 16 + (lane >> 4) * 4 + r;
                    kvf[((size_t)(b * 2 + tensor) * C_ + ch) * PSLAB
                        + (h + 3) * PC_ + (w + 3)] = acc[i][nt][r];
                }
            }
        }
    }
}

// ---- attention: full-unit threads (192/block), fp32 K/V LDS, zero converts ----
__global__ __launch_bounds__(192) void attn_kernel(
    const float* __restrict__ qf, const float* __restrict__ kvf,
    const float* __restrict__ rel, float* __restrict__ out)
{
    const int bx   = blockIdx.x;
    const int tile = bx % 3;
    const int c    = (bx / 3) % C_;
    const int b    = bx / (3 * C_);
    const int ho0  = tile * 32;
    const int t    = threadIdx.x;

    __shared__ __align__(16) float ksl[38 * LDK];
    __shared__ __align__(16) float vsl[38 * LDK];

    {   // stage: 988 float4 chunks each for K and V, aligned linear copies
        const float* kbase = kvf + ((size_t)(b * 2 + 0) * C_ + c) * PSLAB + ho0 * PC_;
        const float* vbase = kvf + ((size_t)(b * 2 + 1) * C_ + c) * PSLAB + ho0 * PC_;
        #pragma unroll
        for (int s0 = 0; s0 < 6; ++s0) {
            const int idx = t + s0 * 192;
            if (idx < 988) {
                const int rl = idx / 26, c4 = (idx - rl * 26) * 4;
                *reinterpret_cast<float4*>(&ksl[rl * LDK + c4]) =
                    *reinterpret_cast<const float4*>(kbase + rl * PC_ + c4);
                *reinterpret_cast<float4*>(&vsl[rl * LDK + c4]) =
                    *reinterpret_cast<const float4*>(vbase + rl * PC_ + c4);
            }
        }
    }
    __syncthreads();

    const int r0 = t / 6;
    const int w0 = (t % 6) * 16;
    const int ho = ho0 + r0;

    const float LOG2E = 1.44269504f;
    const float* qp = qf + ((size_t)b * C_ + c) * NPIX + ho * W_ + w0;
    float qs[16];
    #pragma unroll
    for (int tt = 0; tt < 16; tt += 4) {
        float4 f = *reinterpret_cast<const float4*>(qp + tt);
        qs[tt] = f.x * LOG2E; qs[tt + 1] = f.y * LOG2E;
        qs[tt + 2] = f.z * LOG2E; qs[tt + 3] = f.w * LOG2E;
    }
    float qsum = 0.f;
    #pragma unroll
    for (int tt = 0; tt < 16; ++tt) qsum += qs[tt];

    float p[49];
    #pragma unroll
    for (int i = 0; i < KS_; ++i) {
        float kr[24];
        const float* kp = &ksl[(r0 + i) * LDK + w0];
        #pragma unroll
        for (int tt = 0; tt < 24; tt += 4) {
            float4 f = *reinterpret_cast<const float4*>(kp + tt);
            kr[tt] = f.x; kr[tt + 1] = f.y; kr[tt + 2] = f.z; kr[tt + 3] = f.w;
        }
        #pragma unroll
        for (int j = 0; j < KS_; ++j) {
            float s0 = 0.f, s1 = 0.f, s2 = 0.f, s3 = 0.f;
            #pragma unroll
            for (int tt = 0; tt < 16; tt += 4) {
                s0 = fmaf(qs[tt],     kr[tt + j],     s0);
                s1 = fmaf(qs[tt + 1], kr[tt + 1 + j], s1);
                s2 = fmaf(qs[tt + 2], kr[tt + 2 + j], s2);
                s3 = fmaf(qs[tt + 3], kr[tt + 3 + j], s3);
            }
            p[i * KS_ + j] = (s0 + s1) + (s2 + s3) + qsum * rel[i * KS_ + j];
        }
    }

    // softmax (log2 domain, 4-way trees)
    float m0 = p[0], m1 = p[1], m2 = p[2], m3 = p[3];
    #pragma unroll
    for (int kk = 4; kk < 48; kk += 4) {
        m0 = fmaxf(m0, p[kk]);     m1 = fmaxf(m1, p[kk + 1]);
        m2 = fmaxf(m2, p[kk + 2]); m3 = fmaxf(m3, p[kk + 3]);
    }
    float m = fmaxf(fmaxf(fmaxf(m0, m1), fmaxf(m2, m3)), p[48]);

    float e0 = 0.f, e1 = 0.f, e2 = 0.f, e3 = 0.f;
    #pragma unroll
    for (int kk = 0; kk < 48; kk += 4) {
        float a0 = exp2f(p[kk]     - m);
        float a1 = exp2f(p[kk + 1] - m);
        float a2 = exp2f(p[kk + 2] - m);
        float a3 = exp2f(p[kk + 3] - m);
        p[kk] = a0; p[kk + 1] = a1; p[kk + 2] = a2; p[kk + 3] = a3;
        e0 += a0; e1 += a1; e2 += a2; e3 += a3;
    }
    float a48 = exp2f(p[48] - m);
    p[48] = a48;
    const float inv = 1.f / ((e0 + e1) + (e2 + e3) + a48);

    // PV: full 16 outputs
    float o16[16];
    #pragma unroll
    for (int d = 0; d < 16; ++d) o16[d] = 0.f;

    #pragma unroll
    for (int i = 0; i < KS_; ++i) {
        float vf[24];
        const float* vp = &vsl[(r0 + i) * LDK + w0];
        #pragma unroll
        for (int tt = 0; tt < 24; tt += 4) {
            float4 f = *reinterpret_cast<const float4*>(vp + tt);
            vf[tt] = f.x; vf[tt + 1] = f.y; vf[tt + 2] = f.z; vf[tt + 3] = f.w;
        }
        #pragma unroll
        for (int j = 0; j < KS_; ++j) {
            float wgt = p[i * KS_ + j];
            #pragma unroll
            for (int d = 0; d < 16; ++d) o16[d] = fmaf(wgt, vf[d + j], o16[d]);
        }
    }

    float* op = out + (((size_t)b * C_ + c) * H_ + ho) * W_ + w0;
    #pragma unroll
    for (int d = 0; d < 16; d += 4) {
        float4 f;
        f.x = fmaxf(o16[d]     * inv, 0.f);
        f.y = fmaxf(o16[d + 1] * inv, 0.f);
        f.z = fmaxf(o16[d + 2] * inv, 0.f);
        f.w = fmaxf(o16[d + 3] * inv, 0.f);
        *reinterpret_cast<float4*>(op + d) = f;
    }
}

extern "C" void kernel_launch(void* const* d_in, const int* in_sizes, int n_in,
                              void* d_out, int out_size, void* d_ws, size_t ws_size,
                              hipStream_t stream) {
    const float* in   = (const float*)d_in[0];
    const float* qw   = (const float*)d_in[1];
    const float* qb   = (const float*)d_in[2];
    const float* kw   = (const float*)d_in[3];
    const float* kb   = (const float*)d_in[4];
    const float* vw   = (const float*)d_in[5];
    const float* vb   = (const float*)d_in[6];
    const float* relh = (const float*)d_in[7];
    const float* relw = (const float*)d_in[8];
    float* out = (float*)d_out;

    float* qf  = (float*)d_ws;                             // [B][64][9216]
    float* kvf = qf + (size_t)B_ * C_ * NPIX;              // [B][2][64][102][104]
    float* rel = kvf + (size_t)B_ * 2 * C_ * PSLAB;        // [64]

    dim3 cgrid(NPIX / 32, B_);   // 288 x 4 = 1152 blocks
    mfma_conv_kernel<<<cgrid, 256, 0, stream>>>(in, qw, qb, kw, kb, vw, vb,
                                                relh, relw, qf, kvf, rel);

    dim3 agrid(B_ * C_ * 3);     // 768 blocks x 192 threads
    attn_kernel<<<agrid, 192, 0, stream>>>(qf, kvf, rel, out);
}